// Round 1
// baseline (164.940 us; speedup 1.0000x reference)
//
#include <hip/hip_runtime.h>
#include <math.h>

// EKF propagate: B=65536 elements, nx=16, nz=8, nu=4, fp32.
// 16 lanes per element (lane t owns row t of all 16x16 matrices),
// 4 elements per wave, 16 per block. No __syncthreads: all cross-lane
// traffic is intra-wave via per-group LDS (in-order within one wave's
// instruction stream; __builtin_amdgcn_wave_barrier pins compiler order).
// Each group's LDS slice is touched by exactly one wave.
//
// R5 changes vs R4 (64.9us/dispatch, VALUBusy 62%, Occupancy 40%):
//  1. LDS 27136B -> 19968B => 6 -> 8 blocks/CU (24 -> 32 waves/CU):
//     - TPB (row-major tp copy, 128 floats) dropped; the final Sig_now
//       pass reads the transposed TPT array broadcast-style instead
//       (same read+FMA count, two fewer stores).
//     - VT/TPT stride 20 -> 16 (scatter writes stay conflict-free;
//       the 8 strided b128 reads/lane go to ~2x bank pressure --
//       cheap vs +33% resident waves for latency hiding).
//     - GS = 312 floats: GS%32==24 -> the 4 groups of a wave sit at
//       bank offsets {0,24,16,8} so broadcast reads stay conflict-free;
//       GS%4==0 preserves float4 alignment. 312*16*4 = 19968B.
//  2. tanhf (libm, ~30 instr w/ branches) -> exp2/rcp form (~6 instr).
//     abs err ~1e-7, far below the 1.56e-2 tolerance already consumed
//     by fp32 reassociation.

namespace {

constexpr int GROUPS = 16;            // elements per block
constexpr int TPB    = GROUPS * 16;   // 256 threads

// Per-group LDS layout (floats). Overlays by liveness:
//  [0,256)   VT : V^T, 16 rows x stride 16      [phase V .. W]
//  [0,128)   TPT: tp^T, 8 rows x stride 16      [tp .. final Sig_now]
//  [128,192) SI : S^-1 rows                     [GJ .. K build]
//  [192,208) PIV: pivot row scratch             [GJ only]
//  [256,304) VB : mubar[16] d[16] h[8] dh[8]
constexpr int O_VT  = 0;
constexpr int O_TPT = 0;
constexpr int O_SI  = 128;
constexpr int O_PIV = 192;
constexpr int O_VB  = 256;
constexpr int GS    = 312;  // %32==24: group bank offsets {0,24,16,8}; %4==0

__device__ __forceinline__ float dot4(float4 a, float4 b) {
  return a.x*b.x + a.y*b.y + a.z*b.z + a.w*b.w;
}

// tanh(x) = 1 - 2/(e^{2x}+1); v_exp_f32 + v_rcp_f32, ~1ulp each.
// Saturates correctly for |x| large (e->inf => 1; e->0 => -1).
__device__ __forceinline__ float tanh_fast(float x) {
  float e = __expf(2.0f * x);
  return 1.0f - 2.0f * __builtin_amdgcn_rcpf(e + 1.0f);
}

__global__ __launch_bounds__(TPB)     // NO min-waves: R3's (TPB,6) spilled
void ekf_kernel(const float* __restrict__ mu_prev,
                const float* __restrict__ Sig_prev,
                const float* __restrict__ U,
                const float* __restrict__ Z,
                const float* __restrict__ A,
                const float* __restrict__ Bm,
                const float* __restrict__ C,
                const float* __restrict__ Q,
                const float* __restrict__ R,
                float* __restrict__ mu_out,
                float* __restrict__ sig_out,
                int Btot)
{
  __shared__ float lds[GS * GROUPS];   // 19968 B -> 8 blocks/CU (159744<=163840)
  const int tid = threadIdx.x;
  const int g = tid >> 4;
  const int t = tid & 15;
  int e = blockIdx.x * GROUPS + g;
  if (e >= Btot) e = Btot - 1;         // clamp; duplicate-write benign
  float* L = lds + g * GS;

  // ---- load Sigma row t (coalesced: wave covers a contiguous 4KB) ----
  float sig[16];
  {
    const float4* sp = (const float4*)(Sig_prev + (size_t)e * 256 + t * 16);
    #pragma unroll
    for (int c = 0; c < 4; c++) {
      float4 v = sp[c];
      sig[4*c+0] = v.x; sig[4*c+1] = v.y; sig[4*c+2] = v.z; sig[4*c+3] = v.w;
    }
  }

  // ---- mu_bar_t = tanh(A[t,:].mu + Bm[t,:].u), d_t = 1 - mu_bar^2 ----
  float pre;
  {
    const float4* ar = (const float4*)(A + t * 16);      // L1 row read
    const float4* mr = (const float4*)(mu_prev + (size_t)e * 16);
    pre = dot4(ar[0], mr[0]) + dot4(ar[1], mr[1])
        + dot4(ar[2], mr[2]) + dot4(ar[3], mr[3]);
    float4 b4 = *(const float4*)(Bm + t * 4);
    float4 u4 = *(const float4*)(U + (size_t)e * 4);
    pre += dot4(b4, u4);
  }
  const float mubar = tanh_fast(pre);
  const float dloc  = 1.0f - mubar * mubar;
  L[O_VB + t]      = mubar;
  L[O_VB + 16 + t] = dloc;
  __builtin_amdgcn_wave_barrier();

  // ---- h_bar, dh on lanes t<8 ----
  if (t < 8) {
    const float4* cr = (const float4*)(C + t * 16);
    const float4* mb = (const float4*)(L + O_VB);
    float ph = dot4(cr[0], mb[0]) + dot4(cr[1], mb[1])
             + dot4(cr[2], mb[2]) + dot4(cr[3], mb[3]);
    float hb = tanh_fast(ph);
    L[O_VB + 32 + t] = hb;
    L[O_VB + 40 + t] = 1.0f - hb * hb;
  }
  __builtin_amdgcn_wave_barrier();

  float dh[8];
  {
    float4 d0 = *(const float4*)(L + O_VB + 40);
    float4 d1 = *(const float4*)(L + O_VB + 44);
    dh[0]=d0.x; dh[1]=d0.y; dh[2]=d0.z; dh[3]=d0.w;
    dh[4]=d1.x; dh[5]=d1.y; dh[6]=d1.z; dh[7]=d1.w;
  }

  // ---- V = Sig * A^T (row t local; A rows via s_load), scatter V^T ----
  #pragma unroll
  for (int j = 0; j < 16; j++) {
    float acc = 0.f;
    #pragma unroll
    for (int k = 0; k < 16; k++) acc += sig[k] * A[j*16 + k];  // uniform -> s_load
    L[O_VT + j*16 + t] = acc;       // lane-consecutive banks: conflict-free write
  }
  __builtin_amdgcn_wave_barrier();

  // ---- W col t = A * V[:,t]  (== W row t, W symmetric) ----
  float sb[16];
  {
    float vcol[16];
    const float4* vt = (const float4*)(L + O_VT + t*16);  // ~2x bank pressure, 4 reads
    #pragma unroll
    for (int c = 0; c < 4; c++) {
      float4 v = vt[c];
      vcol[4*c+0]=v.x; vcol[4*c+1]=v.y; vcol[4*c+2]=v.z; vcol[4*c+3]=v.w;
    }
    #pragma unroll
    for (int i = 0; i < 16; i++) {
      float acc = 0.f;
      #pragma unroll
      for (int k = 0; k < 16; k++) acc += A[i*16 + k] * vcol[k]; // s_load
      sb[i] = acc;
    }
  }
  __builtin_amdgcn_wave_barrier();   // VT dead from here; TPT may overlay

  // ---- Sig_bar row t = R[t,:] + d_t * W[t,:] * d ----
  {
    const float4* rr = (const float4*)(R + t * 16);
    const float4* dv = (const float4*)(L + O_VB + 16);
    #pragma unroll
    for (int c = 0; c < 4; c++) {
      float4 r4 = rr[c];
      float4 d4 = dv[c];
      sb[4*c+0] = r4.x + dloc * sb[4*c+0] * d4.x;
      sb[4*c+1] = r4.y + dloc * sb[4*c+1] * d4.y;
      sb[4*c+2] = r4.z + dloc * sb[4*c+2] * d4.z;
      sb[4*c+3] = r4.w + dloc * sb[4*c+3] * d4.w;
    }
  }

  // ---- tp row t = Sig_bar[t,:] C^T Dh ; stash transposed only ----
  float tp[8];
  #pragma unroll
  for (int m = 0; m < 8; m++) {
    float acc = 0.f;
    #pragma unroll
    for (int k = 0; k < 16; k++) acc += sb[k] * C[m*16 + k];    // s_load
    tp[m] = acc * dh[m];
    L[O_TPT + m*16 + t] = tp[m];
  }
  __builtin_amdgcn_wave_barrier();

  // ---- S col t (== row t, S symmetric), Gauss-Jordan inverse (t<8) ----
  if (t < 8) {
    float tcol[16];
    const float4* tt = (const float4*)(L + O_TPT + t*16);
    #pragma unroll
    for (int c = 0; c < 4; c++) {
      float4 v = tt[c];
      tcol[4*c+0]=v.x; tcol[4*c+1]=v.y; tcol[4*c+2]=v.z; tcol[4*c+3]=v.w;
    }
    float s8[8];
    {
      float4 q0 = *(const float4*)(Q + t*8);       // Q row t == col t (sym)
      float4 q1 = *(const float4*)(Q + t*8 + 4);
      float qv[8] = {q0.x,q0.y,q0.z,q0.w,q1.x,q1.y,q1.z,q1.w};
      #pragma unroll
      for (int m = 0; m < 8; m++) {
        float acc = 0.f;
        #pragma unroll
        for (int k = 0; k < 16; k++) acc += C[m*16 + k] * tcol[k]; // s_load
        s8[m] = acc * dh[m] + qv[m];
      }
    }

    // Gauss-Jordan (S is SPD -> no pivoting); rows live in registers.
    float x8[8];
    #pragma unroll
    for (int j = 0; j < 8; j++) x8[j] = (j == t) ? 1.0f : 0.0f;
    #pragma unroll
    for (int p = 0; p < 8; p++) {
      if (t == p) {
        float rcp = 1.0f / s8[p];   // IEEE div (no fast-math)
        #pragma unroll
        for (int j = 0; j < 8; j++) { s8[j] *= rcp; x8[j] *= rcp; }
        *((float4*)(L + O_PIV + 0))  = make_float4(s8[0], s8[1], s8[2], s8[3]);
        *((float4*)(L + O_PIV + 4))  = make_float4(s8[4], s8[5], s8[6], s8[7]);
        *((float4*)(L + O_PIV + 8))  = make_float4(x8[0], x8[1], x8[2], x8[3]);
        *((float4*)(L + O_PIV + 12)) = make_float4(x8[4], x8[5], x8[6], x8[7]);
      }
      __builtin_amdgcn_wave_barrier();
      if (t != p) {
        float f = s8[p];
        float4 pa = *(const float4*)(L + O_PIV + 0);
        float4 pb = *(const float4*)(L + O_PIV + 4);
        float4 pc = *(const float4*)(L + O_PIV + 8);
        float4 pd = *(const float4*)(L + O_PIV + 12);
        s8[0]-=f*pa.x; s8[1]-=f*pa.y; s8[2]-=f*pa.z; s8[3]-=f*pa.w;
        s8[4]-=f*pb.x; s8[5]-=f*pb.y; s8[6]-=f*pb.z; s8[7]-=f*pb.w;
        x8[0]-=f*pc.x; x8[1]-=f*pc.y; x8[2]-=f*pc.z; x8[3]-=f*pc.w;
        x8[4]-=f*pd.x; x8[5]-=f*pd.y; x8[6]-=f*pd.z; x8[7]-=f*pd.w;
      }
      __builtin_amdgcn_wave_barrier();
    }
    *((float4*)(L + O_SI + t*8 + 0)) = make_float4(x8[0], x8[1], x8[2], x8[3]);
    *((float4*)(L + O_SI + t*8 + 4)) = make_float4(x8[4], x8[5], x8[6], x8[7]);
  }
  __builtin_amdgcn_wave_barrier();

  // ---- K row t = tp[t,:] @ Sinv ----
  float kreg[8] = {0,0,0,0,0,0,0,0};
  #pragma unroll
  for (int m = 0; m < 8; m++) {
    float tpm = tp[m];
    float4 a = *(const float4*)(L + O_SI + m*8 + 0);
    float4 b = *(const float4*)(L + O_SI + m*8 + 4);
    kreg[0]+=tpm*a.x; kreg[1]+=tpm*a.y; kreg[2]+=tpm*a.z; kreg[3]+=tpm*a.w;
    kreg[4]+=tpm*b.x; kreg[5]+=tpm*b.y; kreg[6]+=tpm*b.z; kreg[7]+=tpm*b.w;
  }

  // ---- mu_now_t = mu_bar_t + K[t,:].(z - h_bar) ----
  {
    float4 z0 = *(const float4*)(Z + (size_t)e * 8);
    float4 z1 = *(const float4*)(Z + (size_t)e * 8 + 4);
    float4 h0 = *(const float4*)(L + O_VB + 32);
    float4 h1 = *(const float4*)(L + O_VB + 36);
    float mu_now = mubar
      + kreg[0]*(z0.x-h0.x) + kreg[1]*(z0.y-h0.y)
      + kreg[2]*(z0.z-h0.z) + kreg[3]*(z0.w-h0.w)
      + kreg[4]*(z1.x-h1.x) + kreg[5]*(z1.y-h1.y)
      + kreg[6]*(z1.z-h1.z) + kreg[7]*(z1.w-h1.w);
    mu_out[(size_t)e * 16 + t] = mu_now;
  }

  // ---- Sig_now = Sig_bar - K tp^T  (== Joseph form exactly in real
  //      arithmetic, since K S = tp S^-1 S = tp; fp delta ~1e-6).
  //      Consume tp^T from TPT broadcast-style: out[i] -= k[m]*tpT[m][i].
  //      Same 32 b128 reads + 128 FMA as the old TPB path, no TPB copy. ----
  float out[16];
  #pragma unroll
  for (int i = 0; i < 16; i++) out[i] = sb[i];
  #pragma unroll
  for (int m = 0; m < 8; m++) {
    const float km = kreg[m];
    const float4* tr = (const float4*)(L + O_TPT + m*16);  // group-broadcast read
    float4 t0 = tr[0], t1 = tr[1], t2 = tr[2], t3 = tr[3];
    out[0]  -= km*t0.x; out[1]  -= km*t0.y; out[2]  -= km*t0.z; out[3]  -= km*t0.w;
    out[4]  -= km*t1.x; out[5]  -= km*t1.y; out[6]  -= km*t1.z; out[7]  -= km*t1.w;
    out[8]  -= km*t2.x; out[9]  -= km*t2.y; out[10] -= km*t2.z; out[11] -= km*t2.w;
    out[12] -= km*t3.x; out[13] -= km*t3.y; out[14] -= km*t3.z; out[15] -= km*t3.w;
  }
  {
    float4* op = (float4*)(sig_out + (size_t)e * 256 + t * 16);
    op[0] = make_float4(out[0],  out[1],  out[2],  out[3]);
    op[1] = make_float4(out[4],  out[5],  out[6],  out[7]);
    op[2] = make_float4(out[8],  out[9],  out[10], out[11]);
    op[3] = make_float4(out[12], out[13], out[14], out[15]);
  }
}

} // namespace

extern "C" void kernel_launch(void* const* d_in, const int* in_sizes, int n_in,
                              void* d_out, int out_size, void* d_ws, size_t ws_size,
                              hipStream_t stream)
{
  const float* mu_prev = (const float*)d_in[0];
  const float* Sigma   = (const float*)d_in[1];
  const float* u       = (const float*)d_in[2];
  const float* z       = (const float*)d_in[3];
  const float* A       = (const float*)d_in[4];
  const float* Bm      = (const float*)d_in[5];
  const float* C       = (const float*)d_in[6];
  const float* Q       = (const float*)d_in[7];
  const float* R       = (const float*)d_in[8];

  const int Btot = in_sizes[0] / 16;                 // B = 65536
  float* mu_out  = (float*)d_out;
  float* sig_out = (float*)d_out + (size_t)Btot * 16;

  const int grid = (Btot + GROUPS - 1) / GROUPS;     // 4096 blocks x 256 thr
  ekf_kernel<<<grid, TPB, 0, stream>>>(mu_prev, Sigma, u, z, A, Bm, C, Q, R,
                                       mu_out, sig_out, Btot);
}

// Round 2
// 159.673 us; speedup vs baseline: 1.0330x; 1.0330x over previous
//
#include <hip/hip_runtime.h>
#include <math.h>

// EKF propagate: B=65536, nx=16, nz=8, nu=4, fp32.
//
// R6 restructure vs R5 (64.0us/dispatch, VALUBusy 50%, ~11 waves/CU measured):
// R5's null result (LDS 27K->20K + fewer VALU => 0 gain) shows the kernel is
// dependency-LATENCY bound: ~45 serialized lgkm waits/wave, correlated across
// lockstep waves. Changes:
//  1. 8 lanes/element (lane owns rows t and t+8): dual accumulator chains per
//     dependency event, 2x FLOP per uniform s_load operand, half the waves,
//     GJ/S phases fully lane-active (were half-masked).
//  2. Gauss-Jordan pivot broadcast via ds_swizzle (BitMode and=0x18,or=p):
//     zero LDS round trips in GJ (was 16 write->barrier->read chains).
//     Identity-block structure: skip px[j>p] (=delta) and ps[j<p] (~0, dead).
//  3. GS=308 floats (%32==20 -> per-wave group bank offsets all distinct;
//     %4==0 float4-aligned). 39424 B/block -> 4 blocks/CU = 16 waves/CU,
//     matching the ~128 VGPR (4 waves/SIMD) budget.

namespace {

constexpr int LPE    = 8;            // lanes per element
constexpr int GROUPS = 32;           // elements per block
constexpr int TPB    = GROUPS * LPE; // 256 threads

// Per-group LDS layout (floats). Overlays by liveness:
//  [0,256)   VT : VTs[j][r] = V[r][j], 16 rows x 16   [V .. W]
//  [0,128)   TPT: TPT[m][r] = tp[r][m], 8 rows x 16   [tp .. final] (overlay)
//  [128,192) SI : S^-1 rows 8x8                       [post-GJ .. K]
//  [256,272) mubar[16]; [272,288) d[16]; [288,296) h[8]; [296,304) dh[8]
constexpr int O_VT  = 0;
constexpr int O_TPT = 0;
constexpr int O_SI  = 128;
constexpr int O_MU  = 256;
constexpr int O_D   = 272;
constexpr int O_H   = 288;
constexpr int O_DH  = 296;
constexpr int GS    = 308;  // %32==20, %4==0

__device__ __forceinline__ float dot4(float4 a, float4 b) {
  return a.x*b.x + a.y*b.y + a.z*b.z + a.w*b.w;
}

// tanh(x) = 1 - 2/(e^{2x}+1); v_exp_f32 + v_rcp_f32. abs err ~1e-7.
__device__ __forceinline__ float tanh_fast(float x) {
  float e = __expf(2.0f * x);
  return 1.0f - 2.0f * __builtin_amdgcn_rcpf(e + 1.0f);
}

// ds_swizzle BitMode: src_lane = ((lane & 0x18) | P) -> broadcast lane P of
// each 8-lane group (offset imm must be a literal -> macro, not function).
#define SWZF(v, imm) __int_as_float(__builtin_amdgcn_ds_swizzle(__float_as_int(v), (imm)))

// One Gauss-Jordan elimination step for pivot P (P is a literal).
// Rows live in registers: s8[8] (S row t), x8[8] (inverse row t).
// Invariants at entry to step P:
//   - s8[j] maintained for j >= P;  x8[j] maintained for j < P; x8[j>=P]=delta_tj
//   - pivot row's x8[P] == 1 (so px[P]*rp == rp, no swizzle needed)
// f-trick: for t==P, f = ps[P]-1 makes  s8[j] - f*(ps[j]*rp) == ps[j]*rp
// (the normalized pivot row) -- branchless unification, 1 cndmask per step.
#define GJ_STEP(P)                                                         \
  {                                                                        \
    float ps[8], px[8];                                                    \
    _Pragma("unroll")                                                      \
    for (int j = 0; j < 8; j++) {                                          \
      if (j >= (P)) ps[j] = SWZF(s8[j], (((P) << 5) | 0x18));              \
      else          px[j] = SWZF(x8[j], (((P) << 5) | 0x18));              \
    }                                                                      \
    const float rp = __builtin_amdgcn_rcpf(ps[(P)]);                       \
    const float f  = (t == (P)) ? (ps[(P)] - 1.0f) : s8[(P)];              \
    _Pragma("unroll")                                                      \
    for (int j = 0; j < 8; j++) {                                          \
      if (j > (P))      s8[j] -= f * (ps[j] * rp);                         \
      else if (j < (P)) x8[j] -= f * (px[j] * rp);                         \
    }                                                                      \
    x8[(P)] -= f * rp;                                                     \
  }

__global__ __launch_bounds__(TPB)
void ekf_kernel(const float* __restrict__ mu_prev,
                const float* __restrict__ Sig_prev,
                const float* __restrict__ U,
                const float* __restrict__ Z,
                const float* __restrict__ A,
                const float* __restrict__ Bm,
                const float* __restrict__ C,
                const float* __restrict__ Q,
                const float* __restrict__ R,
                float* __restrict__ mu_out,
                float* __restrict__ sig_out,
                int Btot)
{
  __shared__ float lds[GS * GROUPS];   // 39424 B -> 4 blocks/CU
  const int tid = threadIdx.x;
  const int g = tid >> 3;              // group (element) within block
  const int t = tid & 7;               // lane within group
  int e = blockIdx.x * GROUPS + g;
  if (e >= Btot) e = Btot - 1;         // clamp; duplicate-write benign
  float* L = lds + g * GS;
  const int r0 = t, r1 = t + 8;        // owned matrix rows

  // ---- load Sigma rows r0, r1 ----
  float sig0[16], sig1[16];
  {
    const float4* s0 = (const float4*)(Sig_prev + (size_t)e * 256 + r0 * 16);
    const float4* s1 = (const float4*)(Sig_prev + (size_t)e * 256 + r1 * 16);
    #pragma unroll
    for (int c = 0; c < 4; c++) {
      float4 v0 = s0[c], v1 = s1[c];
      sig0[4*c+0]=v0.x; sig0[4*c+1]=v0.y; sig0[4*c+2]=v0.z; sig0[4*c+3]=v0.w;
      sig1[4*c+0]=v1.x; sig1[4*c+1]=v1.y; sig1[4*c+2]=v1.z; sig1[4*c+3]=v1.w;
    }
  }

  // ---- mu_bar rows r0,r1 (dual independent chains) ----
  float mubar0, mubar1, d0loc, d1loc;
  {
    const float4* mr = (const float4*)(mu_prev + (size_t)e * 16);
    float4 m0 = mr[0], m1 = mr[1], m2 = mr[2], m3 = mr[3];
    const float4* a0 = (const float4*)(A + r0 * 16);
    const float4* a1 = (const float4*)(A + r1 * 16);
    float p0 = dot4(a0[0],m0)+dot4(a0[1],m1)+dot4(a0[2],m2)+dot4(a0[3],m3);
    float p1 = dot4(a1[0],m0)+dot4(a1[1],m1)+dot4(a1[2],m2)+dot4(a1[3],m3);
    float4 u4 = *(const float4*)(U + (size_t)e * 4);
    p0 += dot4(*(const float4*)(Bm + r0 * 4), u4);
    p1 += dot4(*(const float4*)(Bm + r1 * 4), u4);
    mubar0 = tanh_fast(p0); d0loc = 1.0f - mubar0 * mubar0;
    mubar1 = tanh_fast(p1); d1loc = 1.0f - mubar1 * mubar1;
  }
  L[O_MU + r0] = mubar0; L[O_MU + r1] = mubar1;
  L[O_D  + r0] = d0loc;  L[O_D  + r1] = d1loc;
  __builtin_amdgcn_wave_barrier();

  // ---- h[t], dh[t]; keep C row t in regs for S-build ----
  float4 ct0, ct1, ct2, ct3;
  float dhl;
  {
    const float4* cr = (const float4*)(C + t * 16);
    ct0 = cr[0]; ct1 = cr[1]; ct2 = cr[2]; ct3 = cr[3];
    const float4* mb = (const float4*)(L + O_MU);
    float ph = dot4(ct0,mb[0])+dot4(ct1,mb[1])+dot4(ct2,mb[2])+dot4(ct3,mb[3]);
    float hb = tanh_fast(ph); dhl = 1.0f - hb * hb;
    L[O_H + t] = hb; L[O_DH + t] = dhl;
  }
  __builtin_amdgcn_wave_barrier();
  float dh[8];
  {
    float4 v0 = *(const float4*)(L + O_DH);
    float4 v1 = *(const float4*)(L + O_DH + 4);
    dh[0]=v0.x; dh[1]=v0.y; dh[2]=v0.z; dh[3]=v0.w;
    dh[4]=v1.x; dh[5]=v1.y; dh[6]=v1.z; dh[7]=v1.w;
  }

  // ---- V = Sig * A^T rows r0,r1; scatter V^T (2 FMA per uniform s_load) ----
  #pragma unroll
  for (int j = 0; j < 16; j++) {
    float acc0 = 0.f, acc1 = 0.f;
    #pragma unroll
    for (int k = 0; k < 16; k++) {
      float a = A[j*16 + k];                  // uniform -> s_load
      acc0 += sig0[k] * a; acc1 += sig1[k] * a;
    }
    L[O_VT + j*16 + r0] = acc0;               // b32 writes: 2-way max
    L[O_VT + j*16 + r1] = acc1;
  }
  __builtin_amdgcn_wave_barrier();

  // ---- W rows r0,r1 (W = A*V, symmetric: col c == row c) ----
  float sb0[16], sb1[16];
  {
    float v0[16], v1[16];
    const float4* p0 = (const float4*)(L + O_VT + r0 * 16);
    const float4* p1 = (const float4*)(L + O_VT + r1 * 16);
    #pragma unroll
    for (int c = 0; c < 4; c++) {
      float4 x0 = p0[c], x1 = p1[c];
      v0[4*c+0]=x0.x; v0[4*c+1]=x0.y; v0[4*c+2]=x0.z; v0[4*c+3]=x0.w;
      v1[4*c+0]=x1.x; v1[4*c+1]=x1.y; v1[4*c+2]=x1.z; v1[4*c+3]=x1.w;
    }
    #pragma unroll
    for (int i = 0; i < 16; i++) {
      float acc0 = 0.f, acc1 = 0.f;
      #pragma unroll
      for (int k = 0; k < 16; k++) {
        float a = A[i*16 + k];                // uniform -> s_load
        acc0 += a * v0[k]; acc1 += a * v1[k];
      }
      sb0[i] = acc0; sb1[i] = acc1;
    }
  }
  __builtin_amdgcn_wave_barrier();            // VT dead; TPT may overlay

  // ---- Sig_bar rows: sb_r = R[r,:] + d_r * W[r,:] * d ----
  {
    const float4* rr0 = (const float4*)(R + r0 * 16);
    const float4* rr1 = (const float4*)(R + r1 * 16);
    const float4* dv  = (const float4*)(L + O_D);
    #pragma unroll
    for (int c = 0; c < 4; c++) {
      float4 ra = rr0[c], rb = rr1[c], dd = dv[c];
      sb0[4*c+0] = ra.x + d0loc*sb0[4*c+0]*dd.x;
      sb0[4*c+1] = ra.y + d0loc*sb0[4*c+1]*dd.y;
      sb0[4*c+2] = ra.z + d0loc*sb0[4*c+2]*dd.z;
      sb0[4*c+3] = ra.w + d0loc*sb0[4*c+3]*dd.w;
      sb1[4*c+0] = rb.x + d1loc*sb1[4*c+0]*dd.x;
      sb1[4*c+1] = rb.y + d1loc*sb1[4*c+1]*dd.y;
      sb1[4*c+2] = rb.z + d1loc*sb1[4*c+2]*dd.z;
      sb1[4*c+3] = rb.w + d1loc*sb1[4*c+3]*dd.w;
    }
  }

  // ---- tp rows r0,r1 = Sig_bar[r,:] C^T Dh ; scatter tp^T ----
  float tp0[8], tp1[8];
  #pragma unroll
  for (int m = 0; m < 8; m++) {
    float acc0 = 0.f, acc1 = 0.f;
    #pragma unroll
    for (int k = 0; k < 16; k++) {
      float c = C[m*16 + k];                  // uniform -> s_load
      acc0 += sb0[k] * c; acc1 += sb1[k] * c;
    }
    tp0[m] = acc0 * dh[m]; tp1[m] = acc1 * dh[m];
    L[O_TPT + m*16 + r0] = tp0[m];
    L[O_TPT + m*16 + r1] = tp1[m];
  }
  __builtin_amdgcn_wave_barrier();

  // ---- S row t = dh_t * (C[t,:] @ tp) + Q[t,:]  (all 8 lanes active;
  //      C row t is in registers -- no uniform stream here) ----
  float s8[8];
  {
    float4 q0 = *(const float4*)(Q + t * 8);
    float4 q1 = *(const float4*)(Q + t * 8 + 4);
    float qv[8] = {q0.x,q0.y,q0.z,q0.w,q1.x,q1.y,q1.z,q1.w};
    #pragma unroll
    for (int m = 0; m < 8; m++) {
      const float4* tr = (const float4*)(L + O_TPT + m * 16);  // broadcast
      float acc = dot4(ct0,tr[0]) + dot4(ct1,tr[1])
                + dot4(ct2,tr[2]) + dot4(ct3,tr[3]);
      s8[m] = acc * dhl + qv[m];
    }
  }

  // ---- Gauss-Jordan inverse of S via swizzle broadcasts (no LDS, no
  //      barriers, all lanes active; S SPD -> no pivoting) ----
  float x8[8];
  #pragma unroll
  for (int j = 0; j < 8; j++) x8[j] = (j == t) ? 1.0f : 0.0f;
  GJ_STEP(0) GJ_STEP(1) GJ_STEP(2) GJ_STEP(3)
  GJ_STEP(4) GJ_STEP(5) GJ_STEP(6) GJ_STEP(7)

  // ---- stash S^-1 rows ----
  *((float4*)(L + O_SI + t*8 + 0)) = make_float4(x8[0], x8[1], x8[2], x8[3]);
  *((float4*)(L + O_SI + t*8 + 4)) = make_float4(x8[4], x8[5], x8[6], x8[7]);
  __builtin_amdgcn_wave_barrier();

  // ---- K rows r0,r1 = tp[r,:] @ Sinv ----
  float k0[8] = {0,0,0,0,0,0,0,0};
  float k1[8] = {0,0,0,0,0,0,0,0};
  #pragma unroll
  for (int m = 0; m < 8; m++) {
    float4 a = *(const float4*)(L + O_SI + m*8 + 0);   // broadcast
    float4 b = *(const float4*)(L + O_SI + m*8 + 4);
    float f0 = tp0[m], f1 = tp1[m];
    k0[0]+=f0*a.x; k0[1]+=f0*a.y; k0[2]+=f0*a.z; k0[3]+=f0*a.w;
    k0[4]+=f0*b.x; k0[5]+=f0*b.y; k0[6]+=f0*b.z; k0[7]+=f0*b.w;
    k1[0]+=f1*a.x; k1[1]+=f1*a.y; k1[2]+=f1*a.z; k1[3]+=f1*a.w;
    k1[4]+=f1*b.x; k1[5]+=f1*b.y; k1[6]+=f1*b.z; k1[7]+=f1*b.w;
  }

  // ---- mu rows r0,r1 ----
  {
    float4 z0 = *(const float4*)(Z + (size_t)e * 8);
    float4 z1 = *(const float4*)(Z + (size_t)e * 8 + 4);
    float4 h0 = *(const float4*)(L + O_H);
    float4 h1 = *(const float4*)(L + O_H + 4);
    float i0=z0.x-h0.x, i1=z0.y-h0.y, i2=z0.z-h0.z, i3=z0.w-h0.w;
    float i4=z1.x-h1.x, i5=z1.y-h1.y, i6=z1.z-h1.z, i7=z1.w-h1.w;
    float mu0 = mubar0 + k0[0]*i0+k0[1]*i1+k0[2]*i2+k0[3]*i3
                       + k0[4]*i4+k0[5]*i5+k0[6]*i6+k0[7]*i7;
    float mu1 = mubar1 + k1[0]*i0+k1[1]*i1+k1[2]*i2+k1[3]*i3
                       + k1[4]*i4+k1[5]*i5+k1[6]*i6+k1[7]*i7;
    mu_out[(size_t)e * 16 + r0] = mu0;
    mu_out[(size_t)e * 16 + r1] = mu1;
  }

  // ---- Sig_now rows = Sig_bar - K tp^T  (K S = tp exactly in real
  //      arithmetic -> equals Joseph form; fp delta ~1e-6) ----
  #pragma unroll
  for (int m = 0; m < 8; m++) {
    const float4* tr = (const float4*)(L + O_TPT + m * 16);  // broadcast
    float4 t0 = tr[0], t1 = tr[1], t2 = tr[2], t3 = tr[3];
    float km0 = k0[m], km1 = k1[m];
    sb0[0] -=km0*t0.x; sb0[1] -=km0*t0.y; sb0[2] -=km0*t0.z; sb0[3] -=km0*t0.w;
    sb0[4] -=km0*t1.x; sb0[5] -=km0*t1.y; sb0[6] -=km0*t1.z; sb0[7] -=km0*t1.w;
    sb0[8] -=km0*t2.x; sb0[9] -=km0*t2.y; sb0[10]-=km0*t2.z; sb0[11]-=km0*t2.w;
    sb0[12]-=km0*t3.x; sb0[13]-=km0*t3.y; sb0[14]-=km0*t3.z; sb0[15]-=km0*t3.w;
    sb1[0] -=km1*t0.x; sb1[1] -=km1*t0.y; sb1[2] -=km1*t0.z; sb1[3] -=km1*t0.w;
    sb1[4] -=km1*t1.x; sb1[5] -=km1*t1.y; sb1[6] -=km1*t1.z; sb1[7] -=km1*t1.w;
    sb1[8] -=km1*t2.x; sb1[9] -=km1*t2.y; sb1[10]-=km1*t2.z; sb1[11]-=km1*t2.w;
    sb1[12]-=km1*t3.x; sb1[13]-=km1*t3.y; sb1[14]-=km1*t3.z; sb1[15]-=km1*t3.w;
  }
  {
    float4* o0 = (float4*)(sig_out + (size_t)e * 256 + r0 * 16);
    float4* o1 = (float4*)(sig_out + (size_t)e * 256 + r1 * 16);
    o0[0] = make_float4(sb0[0],  sb0[1],  sb0[2],  sb0[3]);
    o0[1] = make_float4(sb0[4],  sb0[5],  sb0[6],  sb0[7]);
    o0[2] = make_float4(sb0[8],  sb0[9],  sb0[10], sb0[11]);
    o0[3] = make_float4(sb0[12], sb0[13], sb0[14], sb0[15]);
    o1[0] = make_float4(sb1[0],  sb1[1],  sb1[2],  sb1[3]);
    o1[1] = make_float4(sb1[4],  sb1[5],  sb1[6],  sb1[7]);
    o1[2] = make_float4(sb1[8],  sb1[9],  sb1[10], sb1[11]);
    o1[3] = make_float4(sb1[12], sb1[13], sb1[14], sb1[15]);
  }
}

} // namespace

extern "C" void kernel_launch(void* const* d_in, const int* in_sizes, int n_in,
                              void* d_out, int out_size, void* d_ws, size_t ws_size,
                              hipStream_t stream)
{
  const float* mu_prev = (const float*)d_in[0];
  const float* Sigma   = (const float*)d_in[1];
  const float* u       = (const float*)d_in[2];
  const float* z       = (const float*)d_in[3];
  const float* A       = (const float*)d_in[4];
  const float* Bm      = (const float*)d_in[5];
  const float* C       = (const float*)d_in[6];
  const float* Q       = (const float*)d_in[7];
  const float* R       = (const float*)d_in[8];

  const int Btot = in_sizes[0] / 16;                 // B = 65536
  float* mu_out  = (float*)d_out;
  float* sig_out = (float*)d_out + (size_t)Btot * 16;

  const int grid = (Btot + GROUPS - 1) / GROUPS;     // 2048 blocks x 256 thr
  ekf_kernel<<<grid, TPB, 0, stream>>>(mu_prev, Sigma, u, z, A, Bm, C, Q, R,
                                       mu_out, sig_out, Btot);
}